// Round 11
// baseline (291.320 us; speedup 1.0000x reference)
//
#include <hip/hip_runtime.h>
#include <hip/hip_bf16.h>

#define S_LEN 2048
#define DM 1024
#define NH 16
#define DH 64
#define MROWS 4096  // B*S

typedef __hip_bfloat16 hbf;
typedef __attribute__((ext_vector_type(4))) float floatx4;
typedef __bf16 bf16x8 __attribute__((ext_vector_type(8)));

#define QSCALE 0.18033688f   // 0.125 * log2(e)  (score in log2 domain; exp2 is raw, softmax shift-invariant)

// A/B fragment-linear layout: value T[row16*16+l15][kb*32+quad*8+j] lives at
// frag (row16*(K/32) + kb)*512 + (quad*16+l15)*8 + j  -- every MFMA fragment
// is a contiguous 1KB run, loaded as base + lane*16B (fully coalesced).

// ---------------- 1. fused: X -> A-frag-linear bf16 + W -> B-frag-linear bf16 ----------------
// v3: X path needs no transpose -> load fragment rows DIRECTLY from global
// (2x float4 = 32B contiguous per fragment per lane), skip LDS + barrier.
// W path keeps LDS transpose; float4 loads; wave-coalesced 1KB fragment stores.
__global__ __launch_bounds__(256) void cvt3w(
    const float* __restrict__ q, const float* __restrict__ k, const float* __restrict__ v,
    hbf* __restrict__ Xqh, hbf* __restrict__ Xkh, hbf* __restrict__ Xvh,
    const float* __restrict__ wq, const float* __restrict__ wk,
    const float* __restrict__ wv, const float* __restrict__ wo,
    hbf* __restrict__ Wqh, hbf* __restrict__ Wkh,
    hbf* __restrict__ Wvh, hbf* __restrict__ Woh) {
  __shared__ float tile[64][65];
  const int t = threadIdx.x;
  if (blockIdx.y < 3) {
    // X path: 64 rows x 64 k tile -> 8 fragments of 1KB, direct global->pack->store
    const float* src; hbf* dst;
    switch (blockIdx.y) {
      case 0:  src = q; dst = Xqh; break;
      case 1:  src = k; dst = Xkh; break;
      default: src = v; dst = Xvh; break;
    }
    const int mt = blockIdx.x >> 4, kt = blockIdx.x & 15;
    const int s0 = mt * 64, k0 = kt * 64;
    const int lanep = t & 63, l15p = lanep & 15, quadp = lanep >> 4;
#pragma unroll
    for (int it = 0; it < 2; ++it) {
      int fl = (t >> 6) * 2 + it;     // 0..7
      int fm = fl >> 1, fk = fl & 1;
      const float* rp = &src[(size_t)(s0 + fm * 16 + l15p) * DM + k0 + fk * 32 + quadp * 8];
      const float4 v0 = *(const float4*)rp;
      const float4 v1 = *(const float4*)(rp + 4);
      union { hbf h[8]; uint4 u; } pk;
      pk.h[0] = __float2bfloat16(v0.x); pk.h[1] = __float2bfloat16(v0.y);
      pk.h[2] = __float2bfloat16(v0.z); pk.h[3] = __float2bfloat16(v0.w);
      pk.h[4] = __float2bfloat16(v1.x); pk.h[5] = __float2bfloat16(v1.y);
      pk.h[6] = __float2bfloat16(v1.z); pk.h[7] = __float2bfloat16(v1.w);
      size_t base = ((size_t)(mt * 4 + fm) * 32 + (kt * 2 + fk)) * 512 + lanep * 8;
      *(uint4*)&dst[base] = pk.u;
    }
    return;
  }
  // W path: transpose 64x64 tile via LDS, write B-frag-linear
  const float* W; hbf* Wh;
  switch (blockIdx.x >> 8) {
    case 0:  W = wq; Wh = Wqh; break;
    case 1:  W = wk; Wh = Wkh; break;
    case 2:  W = wv; Wh = Wvh; break;
    default: W = wo; Wh = Woh; break;
  }
  const int t8 = blockIdx.x & 255;
  const int n0 = (t8 & 15) * 64, k0 = (t8 >> 4) * 64;
  const int c4 = (t & 15) * 4, r16 = t >> 4;   // float4 loader coords
#pragma unroll
  for (int i = 0; i < 4; ++i) {
    int row = i * 16 + r16;          // k-local
    const float4 vv = *(const float4*)&W[(size_t)(k0 + row) * DM + n0 + c4];
    tile[row][c4 + 0] = vv.x; tile[row][c4 + 1] = vv.y;
    tile[row][c4 + 2] = vv.z; tile[row][c4 + 3] = vv.w;
  }
  __syncthreads();
  // tile[k_local][n_local] = W[kk][nn]. Lane packs 8 consecutive kk for one nn:
  // nn = n0 + wave*16 + l15, kk = k0 + j*32 + quad*8 + e  ->  run index == lane,
  // so each wave stores one contiguous 1KB fragment per j.
  {
    const int lane = t & 63, l15w = lane & 15, quadw = lane >> 4, wv_ = t >> 6;
    const int nnl = wv_ * 16 + l15w;
#pragma unroll
    for (int j = 0; j < 2; ++j) {
      const int kk0 = j * 32 + quadw * 8;
      union { hbf h[8]; uint4 u; } pk;
#pragma unroll
      for (int e = 0; e < 8; ++e)
        pk.h[e] = __float2bfloat16(tile[kk0 + e][nnl]);
      size_t base = ((size_t)((n0 + nnl) >> 4) * 32 + ((k0 + kk0) >> 5)) * 512 + lane * 8;
      *(uint4*)&Wh[base] = pk.u;
    }
  }
}

// ---------------- 2. QKV projection GEMM v5: 2-way K-split per tile ----------------
// Diagnosis (r10 counters): 52us, MfmaUtil 18%, Occupancy 13%, HBM 15%, VGPR=92 ->
// latency-bound; compiler folded the reg double-buffer; grid 768 = 12 waves/CU.
// Fix: each 64x64 tile computed by 2 waves over K halves (8 iters each), fp32 LDS
// combine (same pattern as flash_attn's ksplit). Grid 1536, 16 waves/CU, total
// L2 traffic UNCHANGED (6144 waves x 128KB = 768MB).
__global__ __launch_bounds__(256, 4) void gemm_qkv(
    const hbf* __restrict__ Xqh, const hbf* __restrict__ Xkh, const hbf* __restrict__ Xvh,
    const hbf* __restrict__ Wqh, const hbf* __restrict__ Wkh, const hbf* __restrict__ Wvh,
    const float* __restrict__ bq, const float* __restrict__ bk, const float* __restrict__ bv,
    hbf* __restrict__ Qh, hbf* __restrict__ Kf, hbf* __restrict__ Vf) {
  const int id = blockIdx.x;             // 1536
  const int x = id & 7, idx = id >> 3;   // XCD x gets m-slice [x*512, x*512+512); idx 0..191
  const int z = idx >> 6, rem = idx & 63;
  const int nblk = rem >> 2, mblk = rem & 3;

  const hbf* Ah; const hbf* Bh; const float* bias; hbf* Out; float oscale;
  if (z == 0)      { Ah = Xqh; Bh = Wqh; bias = bq; Out = Qh; oscale = QSCALE; }
  else if (z == 1) { Ah = Xkh; Bh = Wkh; bias = bk; Out = Kf; oscale = 1.0f; }
  else             { Ah = Xvh; Bh = Wvh; bias = bv; Out = Vf; oscale = 1.0f; }

  const int tid = threadIdx.x;
  const int lane = tid & 63, wave = tid >> 6;
  const int tt = wave >> 1;      // tile within block (0,1)
  const int ks = wave & 1;       // K half
  const int l15 = lane & 15, quad = lane >> 4;
  const int M0 = x * 512 + mblk * 128 + tt * 64;
  const int n0 = nblk * 64;

  __shared__ float Ob[2][64 * 68];   // 2 tiles, stride 68 breaks bank alignment

  const hbf* ap = Ah + (size_t)(M0 >> 4) * 32 * 512 + (size_t)ks * 16 * 512 + lane * 8;
  const hbf* bp = Bh + (size_t)(n0 >> 4) * 32 * 512 + (size_t)ks * 16 * 512 + lane * 8;

  floatx4 acc[4][4] = {};
  bf16x8 a0[4], b0[4], a1[4], b1[4];
#pragma unroll
  for (int i = 0; i < 4; ++i) {
    a0[i] = *(const bf16x8*)&ap[(size_t)i * 16384];
    b0[i] = *(const bf16x8*)&bp[(size_t)i * 16384];
  }

#pragma unroll 1
  for (int kb = 0; kb < 16; kb += 2) {
#pragma unroll
    for (int i = 0; i < 4; ++i) {
      a1[i] = *(const bf16x8*)&ap[(size_t)i * 16384 + (kb + 1) * 512];
      b1[i] = *(const bf16x8*)&bp[(size_t)i * 16384 + (kb + 1) * 512];
    }
    __builtin_amdgcn_s_setprio(1);
#pragma unroll
    for (int mi = 0; mi < 4; ++mi)
#pragma unroll
      for (int ni = 0; ni < 4; ++ni)
        acc[mi][ni] = __builtin_amdgcn_mfma_f32_16x16x32_bf16(a0[mi], b0[ni], acc[mi][ni], 0, 0, 0);
    __builtin_amdgcn_s_setprio(0);
    const int k2 = kb + 2;
    if (k2 < 16) {   // tail guard: dest regs dead after final iter
#pragma unroll
      for (int i = 0; i < 4; ++i) {
        a0[i] = *(const bf16x8*)&ap[(size_t)i * 16384 + k2 * 512];
        b0[i] = *(const bf16x8*)&bp[(size_t)i * 16384 + k2 * 512];
      }
    }
    __builtin_amdgcn_s_setprio(1);
#pragma unroll
    for (int mi = 0; mi < 4; ++mi)
#pragma unroll
      for (int ni = 0; ni < 4; ++ni)
        acc[mi][ni] = __builtin_amdgcn_mfma_f32_16x16x32_bf16(a1[mi], b1[ni], acc[mi][ni], 0, 0, 0);
    __builtin_amdgcn_s_setprio(0);
  }

  // K-split combine: ks==1 writes partials to LDS, ks==0 adds + epilogue
  if (ks == 1) {
    float* Obt = Ob[tt];
#pragma unroll
    for (int mi = 0; mi < 4; ++mi)
#pragma unroll
      for (int ni = 0; ni < 4; ++ni)
#pragma unroll
        for (int r = 0; r < 4; ++r)
          Obt[(mi * 16 + quad * 4 + r) * 68 + ni * 16 + l15] = acc[mi][ni][r];
  }
  __syncthreads();
  if (ks == 0) {
    const float* Obt = Ob[tt];
#pragma unroll
    for (int mi = 0; mi < 4; ++mi) {
#pragma unroll
      for (int ni = 0; ni < 4; ++ni) {
        int col = n0 + ni * 16 + l15;
        float bb_ = bias[col];
#pragma unroll
        for (int r = 0; r < 4; ++r) {
          int row = M0 + mi * 16 + quad * 4 + r;
          float vv = (acc[mi][ni][r] + Obt[(mi * 16 + quad * 4 + r) * 68 + ni * 16 + l15] + bb_) * oscale;
          int b = row >> 11, s = row & 2047, h = col >> 6, dd = col & 63;
          int bh = b * NH + h;
          size_t idxo;
          if (z == 1) {
            int kt = s >> 5, nif = (s >> 4) & 1, fl15 = s & 15;
            int ksf = dd >> 5, fquad = (dd >> 3) & 3, e = dd & 7;
            idxo = (((size_t)bh * 64 + kt) * 4 + ksf * 2 + nif) * 512 + (fquad * 16 + fl15) * 8 + e;
          } else if (z == 2) {
            int kt = s >> 5, u = s & 31;
            int p = 2 * (u & 15) + (u >> 4);   // permuted key slot (matches packed P)
            int fquad = p >> 3, e = p & 7;
            int nd = dd >> 4, fl15 = dd & 15;
            idxo = (((size_t)bh * 64 + kt) * 4 + nd) * 512 + (fquad * 16 + fl15) * 8 + e;
          } else {
            idxo = (((size_t)bh * S_LEN + s) << 6) + dd;
          }
          Out[idxo] = __float2bfloat16(vv);
        }
      }
    }
  }
}

// ---------------- 3. flash attention v10: setprio + guarded last-iter prefetch ----------------
// T5 regime match: barrier-free independently-progressing waves (m191: attn +4-7%).
__global__ __launch_bounds__(256, 4) void flash_attn(
    const hbf* __restrict__ Qh, const hbf* __restrict__ Kf,
    const hbf* __restrict__ Vf, hbf* __restrict__ AO) {
  const int id = blockIdx.x;
  const int bh = (id & 7) * 4 + (id >> 8);     // XCD-local bh group
  const int q0 = ((id >> 3) & 31) * 64;
  const int b = bh >> 4, h = bh & 15;
  const int tid = threadIdx.x;
  const int lane = tid & 63, wave = tid >> 6;
  const int qw = wave & 1;       // q-half within block
  const int ksplit = wave >> 1;  // key half
  const int l15 = lane & 15, quad = lane >> 4;

  __shared__ __align__(16) unsigned char smem[17408];
  __shared__ float Lbuf[2][32];
  hbf* Pw = (hbf*)(smem + wave * 2560);

  const size_t qbase = (((size_t)bh) * S_LEN + q0 + qw * 32) * DH;
  bf16x8 qf[2][2];
#pragma unroll
  for (int mi = 0; mi < 2; ++mi)
#pragma unroll
    for (int ks = 0; ks < 2; ++ks)
      qf[mi][ks] = *(const bf16x8*)&Qh[qbase + (size_t)(mi * 16 + l15) * DH + ks * 32 + quad * 8];

  bf16x8 ones_f;
  {
    const __bf16 ov = (l15 == 0) ? (__bf16)1.0f : (__bf16)0.0f;
#pragma unroll
    for (int j = 0; j < 8; ++j) ones_f[j] = ov;
  }

  floatx4 o[2][4] = {};
  floatx4 lsum[2] = {};

  const hbf* Kb = Kf + ((size_t)bh * 64 + ksplit * 32) * 2048 + lane * 8;
  const hbf* Vb = Vf + ((size_t)bh * 64 + ksplit * 32) * 2048 + lane * 8;

  bf16x8 kf[2][2], vf[4];
#pragma unroll
  for (int ni = 0; ni < 2; ++ni)
#pragma unroll
    for (int ks = 0; ks < 2; ++ks)
      kf[ni][ks] = *(const bf16x8*)&Kb[(ks * 2 + ni) * 512];
#pragma unroll
  for (int nd = 0; nd < 4; ++nd)
    vf[nd] = *(const bf16x8*)&Vb[nd * 512];

#pragma unroll 1
  for (int it = 0; it < 32; ++it) {
    const int tn = (it + 1) * 2048;   // only read under the it<31 guards

    floatx4 sacc[2][2] = {};
    __builtin_amdgcn_s_setprio(1);
#pragma unroll
    for (int ks = 0; ks < 2; ++ks)
#pragma unroll
      for (int mi = 0; mi < 2; ++mi)
#pragma unroll
        for (int ni = 0; ni < 2; ++ni)
          sacc[mi][ni] = __builtin_amdgcn_mfma_f32_16x16x32_bf16(qf[mi][ks], kf[ni][ks], sacc[mi][ni], 0, 0, 0);
    __builtin_amdgcn_s_setprio(0);

    if (it < 31) {   // tail guard: kf dead after final iter
#pragma unroll
      for (int ni = 0; ni < 2; ++ni)
#pragma unroll
        for (int ks = 0; ks < 2; ++ks)
          kf[ni][ks] = *(const bf16x8*)&Kb[tn + (ks * 2 + ni) * 512];
    }

    // p = exp2(s) (raw v_exp; softmax shift-invariance makes the bias unnecessary)
    // packed pair (ni=0,1) -> one b32 store at permuted col 2*l15+ni
#pragma unroll
    for (int mi = 0; mi < 2; ++mi)
#pragma unroll
      for (int r = 0; r < 4; ++r) {
        union { hbf h2[2]; unsigned int u; } pk2;
        pk2.h2[0] = __float2bfloat16(__builtin_amdgcn_exp2f(sacc[mi][0][r]));
        pk2.h2[1] = __float2bfloat16(__builtin_amdgcn_exp2f(sacc[mi][1][r]));
        *(unsigned int*)&Pw[(mi * 16 + quad * 4 + r) * 40 + 2 * l15] = pk2.u;
      }

    bf16x8 pf[2];
#pragma unroll
    for (int mi = 0; mi < 2; ++mi)
      pf[mi] = *(const bf16x8*)&Pw[(mi * 16 + l15) * 40 + quad * 8];

    __builtin_amdgcn_s_setprio(1);
#pragma unroll
    for (int mi = 0; mi < 2; ++mi)
      lsum[mi] = __builtin_amdgcn_mfma_f32_16x16x32_bf16(pf[mi], ones_f, lsum[mi], 0, 0, 0);

#pragma unroll
    for (int nd = 0; nd < 4; ++nd)
#pragma unroll
      for (int mi = 0; mi < 2; ++mi)
        o[mi][nd] = __builtin_amdgcn_mfma_f32_16x16x32_bf16(pf[mi], vf[nd], o[mi][nd], 0, 0, 0);
    __builtin_amdgcn_s_setprio(0);

    if (it < 31) {   // tail guard: vf dead after final iter
#pragma unroll
      for (int nd = 0; nd < 4; ++nd)
        vf[nd] = *(const bf16x8*)&Vb[tn + nd * 512];
    }
  }

  // ---- split-K combine via LDS ----
  __syncthreads();
  if (ksplit == 1) {
    float* Ob = (float*)smem + qw * (32 * 68);
#pragma unroll
    for (int mi = 0; mi < 2; ++mi)
#pragma unroll
      for (int nd = 0; nd < 4; ++nd)
#pragma unroll
        for (int r = 0; r < 4; ++r)
          Ob[(mi * 16 + quad * 4 + r) * 68 + nd * 16 + l15] = o[mi][nd][r];
    if (l15 == 0) {
#pragma unroll
      for (int mi = 0; mi < 2; ++mi)
#pragma unroll
        for (int r = 0; r < 4; ++r)
          Lbuf[qw][mi * 16 + quad * 4 + r] = lsum[mi][r];
    }
  }
  __syncthreads();
  if (ksplit == 0) {
    const float* Ob = (const float*)smem + qw * (32 * 68);
#pragma unroll
    for (int mi = 0; mi < 2; ++mi) {
      float linv[4];
#pragma unroll
      for (int r = 0; r < 4; ++r) {
        float lq = __shfl(lsum[mi][r], lane & 48, 64) + Lbuf[qw][mi * 16 + quad * 4 + r];
        linv[r] = 1.0f / lq;
      }
      const int m16 = (b * S_LEN + q0 + qw * 32 + mi * 16) >> 4;
#pragma unroll
      for (int nd = 0; nd < 4; ++nd) {
        const int kb = h * 2 + (nd >> 1);
        const int qa = ((nd & 1) << 1) + (l15 >> 3);
        const int dd = nd * 16 + l15;
#pragma unroll
        for (int r = 0; r < 4; ++r) {
          int rl = mi * 16 + quad * 4 + r;
          float vv = (o[mi][nd][r] + Ob[rl * 68 + dd]) * linv[r];
          // AO in A-frag-linear layout for gemm_out
          size_t idxo = ((size_t)m16 * 32 + kb) * 512 + (qa * 16 + quad * 4 + r) * 8 + (l15 & 7);
          AO[idxo] = __float2bfloat16(vv);
        }
      }
    }
  }
}

// ---------------- 4. output projection GEMM v4: setprio + guarded tail -> fp32 ----------------
// 32x64 wave-tiles (2048 waves = 8/CU). A = AO-hat (frag-linear), B = Wo-hat.
__global__ __launch_bounds__(256) void gemm_out(
    const hbf* __restrict__ Ah, const hbf* __restrict__ Bh,
    const float* __restrict__ bias, float* __restrict__ Out) {
  const int id = blockIdx.x;             // 512
  const int x = id & 7, idx = id >> 3;   // XCD m-slice
  const int nblk = idx >> 3, mblk = idx & 7;
  const int tid = threadIdx.x;
  const int lane = tid & 63, wave = tid >> 6;
  const int l15 = lane & 15, quad = lane >> 4;
  const int wm = wave >> 1, wn = wave & 1;
  const int M0 = x * 512 + mblk * 64 + wm * 32;
  const int n0 = nblk * 128 + wn * 64;

  const hbf* ap = Ah + (size_t)(M0 >> 4) * 32 * 512 + lane * 8;
  const hbf* bp = Bh + (size_t)(n0 >> 4) * 32 * 512 + lane * 8;

  floatx4 acc[2][4] = {};
  bf16x8 a0[2], b0[4], a1[2], b1[4];
#pragma unroll
  for (int i = 0; i < 2; ++i) a0[i] = *(const bf16x8*)&ap[(size_t)i * 16384];
#pragma unroll
  for (int i = 0; i < 4; ++i) b0[i] = *(const bf16x8*)&bp[(size_t)i * 16384];

#pragma unroll 1
  for (int kb = 0; kb < 32; kb += 2) {
#pragma unroll
    for (int i = 0; i < 2; ++i) a1[i] = *(const bf16x8*)&ap[(size_t)i * 16384 + (kb + 1) * 512];
#pragma unroll
    for (int i = 0; i < 4; ++i) b1[i] = *(const bf16x8*)&bp[(size_t)i * 16384 + (kb + 1) * 512];
    __builtin_amdgcn_s_setprio(1);
#pragma unroll
    for (int mi = 0; mi < 2; ++mi)
#pragma unroll
      for (int ni = 0; ni < 4; ++ni)
        acc[mi][ni] = __builtin_amdgcn_mfma_f32_16x16x32_bf16(a0[mi], b0[ni], acc[mi][ni], 0, 0, 0);
    __builtin_amdgcn_s_setprio(0);
    const int k2 = kb + 2;
    if (k2 < 32) {   // tail guard
#pragma unroll
      for (int i = 0; i < 2; ++i) a0[i] = *(const bf16x8*)&ap[(size_t)i * 16384 + k2 * 512];
#pragma unroll
      for (int i = 0; i < 4; ++i) b0[i] = *(const bf16x8*)&bp[(size_t)i * 16384 + k2 * 512];
    }
    __builtin_amdgcn_s_setprio(1);
#pragma unroll
    for (int mi = 0; mi < 2; ++mi)
#pragma unroll
      for (int ni = 0; ni < 4; ++ni)
        acc[mi][ni] = __builtin_amdgcn_mfma_f32_16x16x32_bf16(a1[mi], b1[ni], acc[mi][ni], 0, 0, 0);
    __builtin_amdgcn_s_setprio(0);
  }

#pragma unroll
  for (int mi = 0; mi < 2; ++mi) {
#pragma unroll
    for (int ni = 0; ni < 4; ++ni) {
      int col = n0 + ni * 16 + l15;
      float bb_ = bias[col];
#pragma unroll
      for (int r = 0; r < 4; ++r) {
        int row = M0 + mi * 16 + quad * 4 + r;
        Out[(size_t)row * DM + col] = acc[mi][ni][r] + bb_;
      }
    }
  }
}

// ---------------- launch ----------------
extern "C" void kernel_launch(void* const* d_in, const int* in_sizes, int n_in,
                              void* d_out, int out_size, void* d_ws, size_t ws_size,
                              hipStream_t stream) {
  const float* v  = (const float*)d_in[0];
  const float* k  = (const float*)d_in[1];
  const float* q  = (const float*)d_in[2];
  const float* wq = (const float*)d_in[3];
  const float* bq = (const float*)d_in[4];
  const float* wk = (const float*)d_in[5];
  const float* bk = (const float*)d_in[6];
  const float* wv = (const float*)d_in[7];
  const float* bv = (const float*)d_in[8];
  const float* wo = (const float*)d_in[9];
  const float* bo = (const float*)d_in[10];

  const size_t NX = (size_t)MROWS * DM;  // 4M elems
  const size_t NW = (size_t)DM * DM;     // 1M elems
  hbf* base = (hbf*)d_ws;
  hbf* Xqh = base;
  hbf* Xkh = Xqh + NX;
  hbf* Xvh = Xkh + NX;
  hbf* Wqh = Xvh + NX;
  hbf* Wkh = Wqh + NW;
  hbf* Wvh = Wkh + NW;
  hbf* Woh = Wvh + NW;
  hbf* Qh  = Woh + NW;
  hbf* Kf  = Qh + NX;
  hbf* Vf  = Kf + NX;
  hbf* AOh = Vf + NX;

  cvt3w<<<dim3(1024, 4), 256, 0, stream>>>(q, k, v, Xqh, Xkh, Xvh,
                                           wq, wk, wv, wo, Wqh, Wkh, Wvh, Woh);
  gemm_qkv<<<1536, 256, 0, stream>>>(Xqh, Xkh, Xvh, Wqh, Wkh, Wvh, bq, bk, bv, Qh, Kf, Vf);
  flash_attn<<<1024, 256, 0, stream>>>(Qh, Kf, Vf, AOh);
  gemm_out<<<512, 256, 0, stream>>>(AOh, Woh, bo, (float*)d_out);
}

// Round 19
// 216.898 us; speedup vs baseline: 1.3431x; 1.3431x over previous
//
#include <hip/hip_runtime.h>
#include <hip/hip_bf16.h>

#define S_LEN 2048
#define DM 1024
#define NH 16
#define DH 64
#define MROWS 4096  // B*S

typedef __hip_bfloat16 hbf;
typedef __attribute__((ext_vector_type(4))) float floatx4;
typedef __bf16 bf16x8 __attribute__((ext_vector_type(8)));

#define QSCALE 0.18033688f   // 0.125 * log2(e)  (score in log2 domain; exp2 is raw, softmax shift-invariant)

// async global->LDS, 16B per lane, wave-uniform LDS base (HW adds lane*16)
#define GLOAD_LDS(g, l) __builtin_amdgcn_global_load_lds(                      \
    (const __attribute__((address_space(1))) void*)(g),                        \
    (__attribute__((address_space(3))) void*)(l), 16, 0, 0)

// A/B fragment-linear layout: value T[row16*16+l15][kb*32+quad*8+j] lives at
// frag (row16*(K/32) + kb)*512 + (quad*16+l15)*8 + j  -- every MFMA fragment
// is a contiguous 1KB run, loaded as base + lane*16B (fully coalesced).

// ---------------- 1. fused: X -> A-frag-linear bf16 + W -> B-frag-linear bf16 ----------------
// v3: X path needs no transpose -> load fragment rows DIRECTLY from global
// (2x float4 = 32B contiguous per fragment per lane), skip LDS + barrier.
// W path keeps LDS transpose; float4 loads; wave-coalesced 1KB fragment stores.
__global__ __launch_bounds__(256) void cvt3w(
    const float* __restrict__ q, const float* __restrict__ k, const float* __restrict__ v,
    hbf* __restrict__ Xqh, hbf* __restrict__ Xkh, hbf* __restrict__ Xvh,
    const float* __restrict__ wq, const float* __restrict__ wk,
    const float* __restrict__ wv, const float* __restrict__ wo,
    hbf* __restrict__ Wqh, hbf* __restrict__ Wkh,
    hbf* __restrict__ Wvh, hbf* __restrict__ Woh) {
  __shared__ float tile[64][65];
  const int t = threadIdx.x;
  if (blockIdx.y < 3) {
    // X path: 64 rows x 64 k tile -> 8 fragments of 1KB, direct global->pack->store
    const float* src; hbf* dst;
    switch (blockIdx.y) {
      case 0:  src = q; dst = Xqh; break;
      case 1:  src = k; dst = Xkh; break;
      default: src = v; dst = Xvh; break;
    }
    const int mt = blockIdx.x >> 4, kt = blockIdx.x & 15;
    const int s0 = mt * 64, k0 = kt * 64;
    const int lanep = t & 63, l15p = lanep & 15, quadp = lanep >> 4;
#pragma unroll
    for (int it = 0; it < 2; ++it) {
      int fl = (t >> 6) * 2 + it;     // 0..7
      int fm = fl >> 1, fk = fl & 1;
      const float* rp = &src[(size_t)(s0 + fm * 16 + l15p) * DM + k0 + fk * 32 + quadp * 8];
      const float4 v0 = *(const float4*)rp;
      const float4 v1 = *(const float4*)(rp + 4);
      union { hbf h[8]; uint4 u; } pk;
      pk.h[0] = __float2bfloat16(v0.x); pk.h[1] = __float2bfloat16(v0.y);
      pk.h[2] = __float2bfloat16(v0.z); pk.h[3] = __float2bfloat16(v0.w);
      pk.h[4] = __float2bfloat16(v1.x); pk.h[5] = __float2bfloat16(v1.y);
      pk.h[6] = __float2bfloat16(v1.z); pk.h[7] = __float2bfloat16(v1.w);
      size_t base = ((size_t)(mt * 4 + fm) * 32 + (kt * 2 + fk)) * 512 + lanep * 8;
      *(uint4*)&dst[base] = pk.u;
    }
    return;
  }
  // W path: transpose 64x64 tile via LDS, write B-frag-linear
  const float* W; hbf* Wh;
  switch (blockIdx.x >> 8) {
    case 0:  W = wq; Wh = Wqh; break;
    case 1:  W = wk; Wh = Wkh; break;
    case 2:  W = wv; Wh = Wvh; break;
    default: W = wo; Wh = Woh; break;
  }
  const int t8 = blockIdx.x & 255;
  const int n0 = (t8 & 15) * 64, k0 = (t8 >> 4) * 64;
  const int c4 = (t & 15) * 4, r16 = t >> 4;   // float4 loader coords
#pragma unroll
  for (int i = 0; i < 4; ++i) {
    int row = i * 16 + r16;          // k-local
    const float4 vv = *(const float4*)&W[(size_t)(k0 + row) * DM + n0 + c4];
    tile[row][c4 + 0] = vv.x; tile[row][c4 + 1] = vv.y;
    tile[row][c4 + 2] = vv.z; tile[row][c4 + 3] = vv.w;
  }
  __syncthreads();
  // tile[k_local][n_local] = W[kk][nn]. Lane packs 8 consecutive kk for one nn:
  // nn = n0 + wave*16 + l15, kk = k0 + j*32 + quad*8 + e  ->  run index == lane,
  // so each wave stores one contiguous 1KB fragment per j.
  {
    const int lane = t & 63, l15w = lane & 15, quadw = lane >> 4, wv_ = t >> 6;
    const int nnl = wv_ * 16 + l15w;
#pragma unroll
    for (int j = 0; j < 2; ++j) {
      const int kk0 = j * 32 + quadw * 8;
      union { hbf h[8]; uint4 u; } pk;
#pragma unroll
      for (int e = 0; e < 8; ++e)
        pk.h[e] = __float2bfloat16(tile[kk0 + e][nnl]);
      size_t base = ((size_t)((n0 + nnl) >> 4) * 32 + ((k0 + kk0) >> 5)) * 512 + lane * 8;
      *(uint4*)&Wh[base] = pk.u;
    }
  }
}

// ---------------- 2. QKV projection GEMM v6: LDS-staged 128x128 block tile ----------------
// r10 counters: 52us no-LDS version latency/L3-BW-bound (MfmaUtil 18%, all idle, 768MB
// operand stream, per-XCD working set 9MB > 4MB L2). r11 K-split spilled (VGPR 64,
// WRITE_SIZE 221MB). v6: m97 pattern -- 4 waves stage A+B fragments via global_load_lds
// (1KB frag = 1 instr/wave), double-buffered LDS (32KB), each wave computes 64x64 of a
// 128x128 block tile with FULL K (no combine). Traffic halves to 384MB. No min-waves
// bound (r11 lesson: that's what forced the spill).
__global__ __launch_bounds__(256) void gemm_qkv(
    const hbf* __restrict__ Xqh, const hbf* __restrict__ Xkh, const hbf* __restrict__ Xvh,
    const hbf* __restrict__ Wqh, const hbf* __restrict__ Wkh, const hbf* __restrict__ Wvh,
    const float* __restrict__ bq, const float* __restrict__ bk, const float* __restrict__ bv,
    hbf* __restrict__ Qh, hbf* __restrict__ Kf, hbf* __restrict__ Vf) {
  const int id = blockIdx.x;             // 768
  const int x = id & 7, idx = id >> 3;   // XCD x gets m-slice [x*512, x*512+512)
  const int z = idx >> 5, rem = idx & 31;
  const int nblk = rem >> 2, mblk = rem & 3;   // nblk 0..7 (128 cols), mblk 0..3 (128 rows)

  const hbf* Ah; const hbf* Bh; const float* bias; hbf* Out; float oscale;
  if (z == 0)      { Ah = Xqh; Bh = Wqh; bias = bq; Out = Qh; oscale = QSCALE; }
  else if (z == 1) { Ah = Xkh; Bh = Wkh; bias = bk; Out = Kf; oscale = 1.0f; }
  else             { Ah = Xvh; Bh = Wvh; bias = bv; Out = Vf; oscale = 1.0f; }

  const int tid = threadIdx.x;
  const int lane = tid & 63, wave = tid >> 6;
  const int wm = wave >> 1, wn = wave & 1;     // 2x2 wave grid over 128x128
  const int l15 = lane & 15, quad = lane >> 4;
  const int M0 = x * 512 + mblk * 128 + wm * 64;
  const int n0 = nblk * 128 + wn * 64;

  __shared__ __align__(16) hbf As[2][8][512];  // [buf][row16-frag][1KB frag]
  __shared__ __align__(16) hbf Bs[2][8][512];  // [buf][col16-frag][1KB frag]

  // staging assignment: waves 0,1 -> A frags 0-3 / 4-7; waves 2,3 -> B frags 0-3 / 4-7
  const int sf = (wave & 1) * 4;
  const bool isB = wave >= 2;
  const int mt16 = (x * 512 + mblk * 128) >> 4;
  const int nt16 = (nblk * 128) >> 4;
  const hbf* gbase = isB ? Bh + (size_t)(nt16 + sf) * 32 * 512 + lane * 8
                         : Ah + (size_t)(mt16 + sf) * 32 * 512 + lane * 8;

  // prologue: stage kb=0 into buf 0
#pragma unroll
  for (int f = 0; f < 4; ++f) {
    const hbf* g = gbase + (size_t)f * 16384;
    if (isB) GLOAD_LDS(g, &Bs[0][sf + f][0]);
    else     GLOAD_LDS(g, &As[0][sf + f][0]);
  }
  __syncthreads();   // compiler drains vmcnt before s_barrier

  floatx4 acc[4][4] = {};
  int buf = 0;
#pragma unroll 1
  for (int kb = 0; kb < 32; ++kb) {
    if (kb < 31) {   // stage next k-step into other buffer (async, lands by end barrier)
      const int nb = buf ^ 1;
#pragma unroll
      for (int f = 0; f < 4; ++f) {
        const hbf* g = gbase + (size_t)f * 16384 + (size_t)(kb + 1) * 512;
        if (isB) GLOAD_LDS(g, &Bs[nb][sf + f][0]);
        else     GLOAD_LDS(g, &As[nb][sf + f][0]);
      }
    }
    bf16x8 a[4], b[4];
#pragma unroll
    for (int i = 0; i < 4; ++i) {
      a[i] = *(const bf16x8*)&As[buf][wm * 4 + i][lane * 8];
      b[i] = *(const bf16x8*)&Bs[buf][wn * 4 + i][lane * 8];
    }
    __builtin_amdgcn_s_setprio(1);
#pragma unroll
    for (int mi = 0; mi < 4; ++mi)
#pragma unroll
      for (int ni = 0; ni < 4; ++ni)
        acc[mi][ni] = __builtin_amdgcn_mfma_f32_16x16x32_bf16(a[mi], b[ni], acc[mi][ni], 0, 0, 0);
    __builtin_amdgcn_s_setprio(0);
    __syncthreads();
    buf ^= 1;
  }

#pragma unroll
  for (int mi = 0; mi < 4; ++mi) {
#pragma unroll
    for (int ni = 0; ni < 4; ++ni) {
      int col = n0 + ni * 16 + l15;
      float bb_ = bias[col];
#pragma unroll
      for (int r = 0; r < 4; ++r) {
        int row = M0 + mi * 16 + quad * 4 + r;
        float vv = (acc[mi][ni][r] + bb_) * oscale;
        int b = row >> 11, s = row & 2047, h = col >> 6, dd = col & 63;
        int bh = b * NH + h;
        size_t idxo;
        if (z == 1) {
          int kt = s >> 5, nif = (s >> 4) & 1, fl15 = s & 15;
          int ksf = dd >> 5, fquad = (dd >> 3) & 3, e = dd & 7;
          idxo = (((size_t)bh * 64 + kt) * 4 + ksf * 2 + nif) * 512 + (fquad * 16 + fl15) * 8 + e;
        } else if (z == 2) {
          int kt = s >> 5, u = s & 31;
          int p = 2 * (u & 15) + (u >> 4);   // permuted key slot (matches packed P)
          int fquad = p >> 3, e = p & 7;
          int nd = dd >> 4, fl15 = dd & 15;
          idxo = (((size_t)bh * 64 + kt) * 4 + nd) * 512 + (fquad * 16 + fl15) * 8 + e;
        } else {
          idxo = (((size_t)bh * S_LEN + s) << 6) + dd;
        }
        Out[idxo] = __float2bfloat16(vv);
      }
    }
  }
}

// ---------------- 3. flash attention v10: setprio + guarded last-iter prefetch ----------------
// T5 regime match: barrier-free independently-progressing waves (m191: attn +4-7%).
__global__ __launch_bounds__(256, 4) void flash_attn(
    const hbf* __restrict__ Qh, const hbf* __restrict__ Kf,
    const hbf* __restrict__ Vf, hbf* __restrict__ AO) {
  const int id = blockIdx.x;
  const int bh = (id & 7) * 4 + (id >> 8);     // XCD-local bh group
  const int q0 = ((id >> 3) & 31) * 64;
  const int b = bh >> 4, h = bh & 15;
  const int tid = threadIdx.x;
  const int lane = tid & 63, wave = tid >> 6;
  const int qw = wave & 1;       // q-half within block
  const int ksplit = wave >> 1;  // key half
  const int l15 = lane & 15, quad = lane >> 4;

  __shared__ __align__(16) unsigned char smem[17408];
  __shared__ float Lbuf[2][32];
  hbf* Pw = (hbf*)(smem + wave * 2560);

  const size_t qbase = (((size_t)bh) * S_LEN + q0 + qw * 32) * DH;
  bf16x8 qf[2][2];
#pragma unroll
  for (int mi = 0; mi < 2; ++mi)
#pragma unroll
    for (int ks = 0; ks < 2; ++ks)
      qf[mi][ks] = *(const bf16x8*)&Qh[qbase + (size_t)(mi * 16 + l15) * DH + ks * 32 + quad * 8];

  bf16x8 ones_f;
  {
    const __bf16 ov = (l15 == 0) ? (__bf16)1.0f : (__bf16)0.0f;
#pragma unroll
    for (int j = 0; j < 8; ++j) ones_f[j] = ov;
  }

  floatx4 o[2][4] = {};
  floatx4 lsum[2] = {};

  const hbf* Kb = Kf + ((size_t)bh * 64 + ksplit * 32) * 2048 + lane * 8;
  const hbf* Vb = Vf + ((size_t)bh * 64 + ksplit * 32) * 2048 + lane * 8;

  bf16x8 kf[2][2], vf[4];
#pragma unroll
  for (int ni = 0; ni < 2; ++ni)
#pragma unroll
    for (int ks = 0; ks < 2; ++ks)
      kf[ni][ks] = *(const bf16x8*)&Kb[(ks * 2 + ni) * 512];
#pragma unroll
  for (int nd = 0; nd < 4; ++nd)
    vf[nd] = *(const bf16x8*)&Vb[nd * 512];

#pragma unroll 1
  for (int it = 0; it < 32; ++it) {
    const int tn = (it + 1) * 2048;   // only read under the it<31 guards

    floatx4 sacc[2][2] = {};
    __builtin_amdgcn_s_setprio(1);
#pragma unroll
    for (int ks = 0; ks < 2; ++ks)
#pragma unroll
      for (int mi = 0; mi < 2; ++mi)
#pragma unroll
        for (int ni = 0; ni < 2; ++ni)
          sacc[mi][ni] = __builtin_amdgcn_mfma_f32_16x16x32_bf16(qf[mi][ks], kf[ni][ks], sacc[mi][ni], 0, 0, 0);
    __builtin_amdgcn_s_setprio(0);

    if (it < 31) {   // tail guard: kf dead after final iter
#pragma unroll
      for (int ni = 0; ni < 2; ++ni)
#pragma unroll
        for (int ks = 0; ks < 2; ++ks)
          kf[ni][ks] = *(const bf16x8*)&Kb[tn + (ks * 2 + ni) * 512];
    }

    // p = exp2(s) (raw v_exp; softmax shift-invariance makes the bias unnecessary)
    // packed pair (ni=0,1) -> one b32 store at permuted col 2*l15+ni
#pragma unroll
    for (int mi = 0; mi < 2; ++mi)
#pragma unroll
      for (int r = 0; r < 4; ++r) {
        union { hbf h2[2]; unsigned int u; } pk2;
        pk2.h2[0] = __float2bfloat16(__builtin_amdgcn_exp2f(sacc[mi][0][r]));
        pk2.h2[1] = __float2bfloat16(__builtin_amdgcn_exp2f(sacc[mi][1][r]));
        *(unsigned int*)&Pw[(mi * 16 + quad * 4 + r) * 40 + 2 * l15] = pk2.u;
      }

    bf16x8 pf[2];
#pragma unroll
    for (int mi = 0; mi < 2; ++mi)
      pf[mi] = *(const bf16x8*)&Pw[(mi * 16 + l15) * 40 + quad * 8];

    __builtin_amdgcn_s_setprio(1);
#pragma unroll
    for (int mi = 0; mi < 2; ++mi)
      lsum[mi] = __builtin_amdgcn_mfma_f32_16x16x32_bf16(pf[mi], ones_f, lsum[mi], 0, 0, 0);

#pragma unroll
    for (int nd = 0; nd < 4; ++nd)
#pragma unroll
      for (int mi = 0; mi < 2; ++mi)
        o[mi][nd] = __builtin_amdgcn_mfma_f32_16x16x32_bf16(pf[mi], vf[nd], o[mi][nd], 0, 0, 0);
    __builtin_amdgcn_s_setprio(0);

    if (it < 31) {   // tail guard: vf dead after final iter
#pragma unroll
      for (int nd = 0; nd < 4; ++nd)
        vf[nd] = *(const bf16x8*)&Vb[tn + nd * 512];
    }
  }

  // ---- split-K combine via LDS ----
  __syncthreads();
  if (ksplit == 1) {
    float* Ob = (float*)smem + qw * (32 * 68);
#pragma unroll
    for (int mi = 0; mi < 2; ++mi)
#pragma unroll
      for (int nd = 0; nd < 4; ++nd)
#pragma unroll
        for (int r = 0; r < 4; ++r)
          Ob[(mi * 16 + quad * 4 + r) * 68 + nd * 16 + l15] = o[mi][nd][r];
    if (l15 == 0) {
#pragma unroll
      for (int mi = 0; mi < 2; ++mi)
#pragma unroll
        for (int r = 0; r < 4; ++r)
          Lbuf[qw][mi * 16 + quad * 4 + r] = lsum[mi][r];
    }
  }
  __syncthreads();
  if (ksplit == 0) {
    const float* Ob = (const float*)smem + qw * (32 * 68);
#pragma unroll
    for (int mi = 0; mi < 2; ++mi) {
      float linv[4];
#pragma unroll
      for (int r = 0; r < 4; ++r) {
        float lq = __shfl(lsum[mi][r], lane & 48, 64) + Lbuf[qw][mi * 16 + quad * 4 + r];
        linv[r] = 1.0f / lq;
      }
      const int m16 = (b * S_LEN + q0 + qw * 32 + mi * 16) >> 4;
#pragma unroll
      for (int nd = 0; nd < 4; ++nd) {
        const int kb = h * 2 + (nd >> 1);
        const int qa = ((nd & 1) << 1) + (l15 >> 3);
        const int dd = nd * 16 + l15;
#pragma unroll
        for (int r = 0; r < 4; ++r) {
          int rl = mi * 16 + quad * 4 + r;
          float vv = (o[mi][nd][r] + Ob[rl * 68 + dd]) * linv[r];
          // AO in A-frag-linear layout for gemm_out
          size_t idxo = ((size_t)m16 * 32 + kb) * 512 + (qa * 16 + quad * 4 + r) * 8 + (l15 & 7);
          AO[idxo] = __float2bfloat16(vv);
        }
      }
    }
  }
}

// ---------------- 4. output projection GEMM v4: setprio + guarded tail -> fp32 ----------------
// 32x64 wave-tiles (2048 waves = 8/CU). A = AO-hat (frag-linear), B = Wo-hat.
__global__ __launch_bounds__(256) void gemm_out(
    const hbf* __restrict__ Ah, const hbf* __restrict__ Bh,
    const float* __restrict__ bias, float* __restrict__ Out) {
  const int id = blockIdx.x;             // 512
  const int x = id & 7, idx = id >> 3;   // XCD m-slice
  const int nblk = idx >> 3, mblk = idx & 7;
  const int tid = threadIdx.x;
  const int lane = tid & 63, wave = tid >> 6;
  const int l15 = lane & 15, quad = lane >> 4;
  const int wm = wave >> 1, wn = wave & 1;
  const int M0 = x * 512 + mblk * 64 + wm * 32;
  const int n0 = nblk * 128 + wn * 64;

  const hbf* ap = Ah + (size_t)(M0 >> 4) * 32 * 512 + lane * 8;
  const hbf* bp = Bh + (size_t)(n0 >> 4) * 32 * 512 + lane * 8;

  floatx4 acc[2][4] = {};
  bf16x8 a0[2], b0[4], a1[2], b1[4];
#pragma unroll
  for (int i = 0; i < 2; ++i) a0[i] = *(const bf16x8*)&ap[(size_t)i * 16384];
#pragma unroll
  for (int i = 0; i < 4; ++i) b0[i] = *(const bf16x8*)&bp[(size_t)i * 16384];

#pragma unroll 1
  for (int kb = 0; kb < 32; kb += 2) {
#pragma unroll
    for (int i = 0; i < 2; ++i) a1[i] = *(const bf16x8*)&ap[(size_t)i * 16384 + (kb + 1) * 512];
#pragma unroll
    for (int i = 0; i < 4; ++i) b1[i] = *(const bf16x8*)&bp[(size_t)i * 16384 + (kb + 1) * 512];
    __builtin_amdgcn_s_setprio(1);
#pragma unroll
    for (int mi = 0; mi < 2; ++mi)
#pragma unroll
      for (int ni = 0; ni < 4; ++ni)
        acc[mi][ni] = __builtin_amdgcn_mfma_f32_16x16x32_bf16(a0[mi], b0[ni], acc[mi][ni], 0, 0, 0);
    __builtin_amdgcn_s_setprio(0);
    const int k2 = kb + 2;
    if (k2 < 32) {   // tail guard
#pragma unroll
      for (int i = 0; i < 2; ++i) a0[i] = *(const bf16x8*)&ap[(size_t)i * 16384 + k2 * 512];
#pragma unroll
      for (int i = 0; i < 4; ++i) b0[i] = *(const bf16x8*)&bp[(size_t)i * 16384 + k2 * 512];
    }
    __builtin_amdgcn_s_setprio(1);
#pragma unroll
    for (int mi = 0; mi < 2; ++mi)
#pragma unroll
      for (int ni = 0; ni < 4; ++ni)
        acc[mi][ni] = __builtin_amdgcn_mfma_f32_16x16x32_bf16(a1[mi], b1[ni], acc[mi][ni], 0, 0, 0);
    __builtin_amdgcn_s_setprio(0);
  }

#pragma unroll
  for (int mi = 0; mi < 2; ++mi) {
#pragma unroll
    for (int ni = 0; ni < 4; ++ni) {
      int col = n0 + ni * 16 + l15;
      float bb_ = bias[col];
#pragma unroll
      for (int r = 0; r < 4; ++r) {
        int row = M0 + mi * 16 + quad * 4 + r;
        Out[(size_t)row * DM + col] = acc[mi][ni][r] + bb_;
      }
    }
  }
}

// ---------------- launch ----------------
extern "C" void kernel_launch(void* const* d_in, const int* in_sizes, int n_in,
                              void* d_out, int out_size, void* d_ws, size_t ws_size,
                              hipStream_t stream) {
  const float* v  = (const float*)d_in[0];
  const float* k  = (const float*)d_in[1];
  const float* q  = (const float*)d_in[2];
  const float* wq = (const float*)d_in[3];
  const float* bq = (const float*)d_in[4];
  const float* wk = (const float*)d_in[5];
  const float* bk = (const float*)d_in[6];
  const float* wv = (const float*)d_in[7];
  const float* bv = (const float*)d_in[8];
  const float* wo = (const float*)d_in[9];
  const float* bo = (const float*)d_in[10];

  const size_t NX = (size_t)MROWS * DM;  // 4M elems
  const size_t NW = (size_t)DM * DM;     // 1M elems
  hbf* base = (hbf*)d_ws;
  hbf* Xqh = base;
  hbf* Xkh = Xqh + NX;
  hbf* Xvh = Xkh + NX;
  hbf* Wqh = Xvh + NX;
  hbf* Wkh = Wqh + NW;
  hbf* Wvh = Wkh + NW;
  hbf* Woh = Wvh + NW;
  hbf* Qh  = Woh + NW;
  hbf* Kf  = Qh + NX;
  hbf* Vf  = Kf + NX;
  hbf* AOh = Vf + NX;

  cvt3w<<<dim3(1024, 4), 256, 0, stream>>>(q, k, v, Xqh, Xkh, Xvh,
                                           wq, wk, wv, wo, Wqh, Wkh, Wvh, Woh);
  gemm_qkv<<<768, 256, 0, stream>>>(Xqh, Xkh, Xvh, Wqh, Wkh, Wvh, bq, bk, bv, Qh, Kf, Vf);
  flash_attn<<<1024, 256, 0, stream>>>(Qh, Kf, Vf, AOh);
  gemm_out<<<512, 256, 0, stream>>>(AOh, Woh, bo, (float*)d_out);
}